// Round 10
// baseline (893.973 us; speedup 1.0000x reference)
//
#include <hip/hip_runtime.h>

#define S_LEN 2048
#define D_DIM 1024
#define H_DIM 4096
#define V_DIM 32000
#define B_SZ  4

typedef float  f32x4  __attribute__((ext_vector_type(4)));
typedef __bf16 bf16x8 __attribute__((ext_vector_type(8)));

__device__ __forceinline__ ushort f2bf(float f) {
    union { float f; unsigned u; } v; v.f = f;
    unsigned r = v.u + 0x7fffu + ((v.u >> 16) & 1u);
    return (ushort)(r >> 16);
}

// ---------------------------------------------------------------------------
// Weight transpose + fp32->bf16 convert: in fp32 [R][C] -> out bf16 [C][R]
// ---------------------------------------------------------------------------
__global__ void bt_wtranspose(const float* __restrict__ in, ushort* __restrict__ out,
                              int R, int C) {
    __shared__ ushort s[64][65];
    int r0 = blockIdx.y * 64, c0 = blockIdx.x * 64;
    int t = threadIdx.x;
    int lr = t >> 2, lc4 = (t & 3) * 16;
    const float* src = in + (size_t)(r0 + lr) * C + c0 + lc4;
#pragma unroll
    for (int j = 0; j < 4; ++j) {
        float4 v = ((const float4*)src)[j];
        s[lr][lc4 + 4 * j + 0] = f2bf(v.x);
        s[lr][lc4 + 4 * j + 1] = f2bf(v.y);
        s[lr][lc4 + 4 * j + 2] = f2bf(v.z);
        s[lr][lc4 + 4 * j + 3] = f2bf(v.w);
    }
    __syncthreads();
    int oc = t >> 2, orr = (t & 3) * 16;
    ushort tmp[16] __attribute__((aligned(16)));
#pragma unroll
    for (int j = 0; j < 16; ++j) tmp[j] = s[orr + j][oc];
    ushort* dst = out + (size_t)(c0 + oc) * R + r0 + orr;
    *(uint4*)dst        = *(uint4*)tmp;
    *(uint4*)(dst + 8)  = *(uint4*)(tmp + 8);
}

// ---------------------------------------------------------------------------
// bf16 transpose of a column slice: out[c][r] = in[r][coff + c]
// ---------------------------------------------------------------------------
__global__ void bt_transpose(const ushort* __restrict__ in, ushort* __restrict__ out,
                             int R, int ldin, int coff) {
    __shared__ ushort s[64][65];
    int r0 = blockIdx.y * 64, c0 = blockIdx.x * 64;
    int t = threadIdx.x;
    int lr = t >> 2, lc = (t & 3) * 16;
    const ushort* src = in + (size_t)(r0 + lr) * ldin + coff + c0 + lc;
    uint4 v0 = ((const uint4*)src)[0];
    uint4 v1 = ((const uint4*)src)[1];
    ushort tin[16] __attribute__((aligned(16)));
    *(uint4*)tin = v0; *(uint4*)(tin + 8) = v1;
#pragma unroll
    for (int j = 0; j < 16; ++j) s[lr][lc + j] = tin[j];
    __syncthreads();
    int oc = t >> 2, orr = (t & 3) * 16;
    ushort tmp[16] __attribute__((aligned(16)));
#pragma unroll
    for (int j = 0; j < 16; ++j) tmp[j] = s[orr + j][oc];
    ushort* dst = out + (size_t)(c0 + oc) * R + r0 + orr;
    *(uint4*)dst       = *(uint4*)tmp;
    *(uint4*)(dst + 8) = *(uint4*)(tmp + 8);
}

// ---------------------------------------------------------------------------
// Embedding + positional encoding
// ---------------------------------------------------------------------------
__global__ void bt_embed(const int* __restrict__ tokens, const float* __restrict__ emb,
                         const float* __restrict__ pe, float* __restrict__ h,
                         ushort* __restrict__ hbf) {
    int row = blockIdx.x;
    int s   = row & (S_LEN - 1);
    int tok = tokens[row];
    int t   = threadIdx.x;
    float4 v = ((const float4*)(emb + (size_t)tok * D_DIM))[t];
    float4 p = ((const float4*)(pe + (size_t)s * D_DIM))[t];
    v.x += p.x; v.y += p.y; v.z += p.z; v.w += p.w;
    ((float4*)(h + (size_t)row * D_DIM))[t] = v;
    uint2 pk;
    pk.x = (unsigned)f2bf(v.x) | ((unsigned)f2bf(v.y) << 16);
    pk.y = (unsigned)f2bf(v.z) | ((unsigned)f2bf(v.w) << 16);
    ((uint2*)(hbf + (size_t)row * D_DIM))[t] = pk;
}

// ---------------------------------------------------------------------------
// m97-structure GEMM (calibration): 128x128 tile, 4 waves (2x2), acc 4x4,
// SINGLE 32KB LDS buffer, two __syncthreads per K=64 step, compiler-managed
// waitcnts (no manual vmcnt/setprio/sched_barrier). 32KB LDS + ~64 VGPR ->
// 4-5 blocks/CU: inter-block overlap (m114) instead of intra-block pipeline.
// XCD band swizzle (R4-proven, -70% FETCH) kept.
// ---------------------------------------------------------------------------
#define EPI_F32  0
#define EPI_BF16 1
#define EPI_RELU 2
#define EPI_RES  3

#define AS1 __attribute__((address_space(1)))
#define AS3 __attribute__((address_space(3)))

template <int EPI, bool CSKIP, bool KLIM, int SWZ>
__global__ __launch_bounds__(256, 2)
void bt_gemm(const ushort* __restrict__ A, const ushort* __restrict__ B,
             float* Cf, ushort* Cb, const float* __restrict__ Res,
             int lda, int ldb, int ldc, int K,
             size_t strideA, size_t strideB, size_t strideC) {
    __shared__ ushort sA[128 * 64];
    __shared__ ushort sB[128 * 64];

    int bm, bn;
    if (SWZ == 1) {               // XCD owns a band of bm rows (gy % 8 == 0)
        int gx = gridDim.x, gy = gridDim.y;
        int id = blockIdx.y * gx + blockIdx.x;
        int xcd = id & 7, slot = id >> 3;
        int bandH = gy >> 3;
        bm = xcd * bandH + (slot % bandH);
        bn = slot / bandH;
    } else { bm = blockIdx.y; bn = blockIdx.x; }

    if (CSKIP && bn > bm) return;       // causal: tile fully above diagonal

    const int tid  = threadIdx.x;
    const int lane = tid & 63;
    const int wv   = tid >> 6;
    const int wr   = wv >> 1, wc = wv & 1;
    const int r15  = lane & 15, r4 = lane >> 4;

    const ushort* Ab = A + strideA * blockIdx.z + (size_t)bm * 128 * lda;
    const ushort* Bb = B + strideB * blockIdx.z + (size_t)bn * 128 * ldb;

    int ktiles = K >> 6;
    if (KLIM) { int lim = (bm + 1) * 2; if (lim < ktiles) ktiles = lim; }

    f32x4 acc[4][4];
#pragma unroll
    for (int m = 0; m < 4; ++m)
#pragma unroll
        for (int n = 0; n < 4; ++n) acc[m][n] = (f32x4){0.f, 0.f, 0.f, 0.f};

    const int srow = wv * 8 + (lane >> 3);  // staging row within 32-row round
    const int sout = lane & 7;              // destination 16B slot within row

    for (int kt = 0; kt < ktiles; ++kt) {
        __syncthreads();                    // protect LDS from overwrite
        const ushort* Ak = Ab + kt * 64;
        const ushort* Bk = Bb + kt * 64;
#pragma unroll
        for (int j = 0; j < 4; ++j) {
            int row = j * 32 + srow;
            int si  = sout ^ (row & 7);     // pre-swizzled global source slot
            __builtin_amdgcn_global_load_lds(
                (const AS1 void*)(Ak + (size_t)row * lda + si * 8),
                (AS3 void*)(sA + j * 2048 + wv * 512), 16, 0, 0);
        }
#pragma unroll
        for (int j = 0; j < 4; ++j) {
            int row = j * 32 + srow;
            int si  = sout ^ (row & 7);
            __builtin_amdgcn_global_load_lds(
                (const AS1 void*)(Bk + (size_t)row * ldb + si * 8),
                (AS3 void*)(sB + j * 2048 + wv * 512), 16, 0, 0);
        }
        __syncthreads();                    // drains vmcnt + barrier
#pragma unroll
        for (int kk = 0; kk < 2; ++kk) {
            bf16x8 af[4], bv[4];
            int s = kk * 4 + r4;
#pragma unroll
            for (int m = 0; m < 4; ++m) {
                int row = wr * 64 + m * 16 + r15;
                af[m] = *(const bf16x8*)(sA + (size_t)row * 64 + (size_t)((s ^ (row & 7)) * 8));
            }
#pragma unroll
            for (int n = 0; n < 4; ++n) {
                int col = wc * 64 + n * 16 + r15;
                bv[n] = *(const bf16x8*)(sB + (size_t)col * 64 + (size_t)((s ^ (col & 7)) * 8));
            }
#pragma unroll
            for (int m = 0; m < 4; ++m)
#pragma unroll
                for (int n = 0; n < 4; ++n)
                    acc[m][n] = __builtin_amdgcn_mfma_f32_16x16x32_bf16(af[m], bv[n], acc[m][n], 0, 0, 0);
        }
    }

    // epilogue: frag row = 4*(lane>>4)+r, col = lane&15
    size_t cz = strideC * blockIdx.z;
    const int rowb = bm * 128 + wr * 64 + r4 * 4;
    const int colb = bn * 128 + wc * 64 + r15;
#pragma unroll
    for (int m = 0; m < 4; ++m) {
#pragma unroll
        for (int r = 0; r < 4; ++r) {
            int row = rowb + m * 16 + r;
            size_t base = cz + (size_t)row * ldc + colb;
#pragma unroll
            for (int n = 0; n < 4; ++n) {
                float v = acc[m][n][r];
                size_t idx = base + n * 16;
                if (EPI == EPI_F32)       Cf[idx] = v;
                else if (EPI == EPI_BF16) Cb[idx] = f2bf(v);
                else if (EPI == EPI_RELU) Cb[idx] = f2bf(fmaxf(v, 0.f));
                else { float o = v + Res[idx]; Cf[idx] = o; Cb[idx] = f2bf(o); }
            }
        }
    }
}

// ---------------------------------------------------------------------------
// Causal row softmax: scores fp32 [B][S][S] -> probs bf16 (zeros above diag)
// ---------------------------------------------------------------------------
__device__ __forceinline__ float wred_max(float v) {
#pragma unroll
    for (int off = 32; off; off >>= 1) v = fmaxf(v, __shfl_xor(v, off));
    return v;
}
__device__ __forceinline__ float wred_sum(float v) {
#pragma unroll
    for (int off = 32; off; off >>= 1) v += __shfl_xor(v, off);
    return v;
}

__global__ void bt_softmax(const float* __restrict__ scores, ushort* __restrict__ probs) {
    int row = blockIdx.x;
    int s   = row & (S_LEN - 1);
    const float* src = scores + (size_t)row * S_LEN;
    ushort*      dst = probs  + (size_t)row * S_LEN;
    int tid = threadIdx.x;
    int nvalid = s + 1;

    float vals[8];
    float mx = -1e30f;
#pragma unroll
    for (int j = 0; j < 8; ++j) {
        int t = tid + j * 256;
        float v = (t < nvalid) ? src[t] * 0.03125f : -1e30f;
        vals[j] = v;
        mx = fmaxf(mx, v);
    }
    __shared__ float red[4], red2[4];
    mx = wred_max(mx);
    if ((tid & 63) == 0) red[tid >> 6] = mx;
    __syncthreads();
    mx = fmaxf(fmaxf(red[0], red[1]), fmaxf(red[2], red[3]));

    float sum = 0.f, ps[8];
#pragma unroll
    for (int j = 0; j < 8; ++j) {
        float p = exp2f((vals[j] - mx) * 1.44269504f);
        ps[j] = p; sum += p;
    }
    sum = wred_sum(sum);
    if ((tid & 63) == 0) red2[tid >> 6] = sum;
    __syncthreads();
    sum = red2[0] + red2[1] + red2[2] + red2[3];
    float inv = 1.0f / sum;
#pragma unroll
    for (int j = 0; j < 8; ++j) {
        int t = tid + j * 256;
        dst[t] = (t < nvalid) ? f2bf(ps[j] * inv) : (ushort)0;
    }
}

// ---------------------------------------------------------------------------
// Last-token logits
// ---------------------------------------------------------------------------
__global__ void bt_logits(const float* __restrict__ h, const float* __restrict__ wout,
                          float* __restrict__ out) {
    __shared__ float hl[4][128];
    int tid = threadIdx.x;
    int d0 = blockIdx.y * 128;
    if (tid < 128) {
#pragma unroll
        for (int b = 0; b < 4; ++b)
            hl[b][tid] = h[((size_t)b * S_LEN + (S_LEN - 1)) * D_DIM + d0 + tid];
    }
    __syncthreads();
    int v = blockIdx.x * 256 + tid;
    float a0 = 0, a1 = 0, a2 = 0, a3 = 0;
    for (int j = 0; j < 128; ++j) {
        float w = wout[(size_t)(d0 + j) * V_DIM + v];
        a0 += hl[0][j] * w; a1 += hl[1][j] * w;
        a2 += hl[2][j] * w; a3 += hl[3][j] * w;
    }
    atomicAdd(out + v, a0);
    atomicAdd(out + V_DIM + v, a1);
    atomicAdd(out + 2 * V_DIM + v, a2);
    atomicAdd(out + 3 * V_DIM + v, a3);
}

// ---------------------------------------------------------------------------
extern "C" void kernel_launch(void* const* d_in, const int* in_sizes, int n_in,
                              void* d_out, int out_size, void* d_ws, size_t ws_size,
                              hipStream_t stream) {
    const int*   tokens = (const int*)d_in[0];
    const float* emb    = (const float*)d_in[1];
    const float* pe     = (const float*)d_in[2];
    const float* wout = (const float*)d_in[13];

    char* w = (char*)d_ws;
    size_t o = 0;
    auto take = [&](size_t sz) { char* p = w + o; o += (sz + 255) & ~(size_t)255; return p; };

    const size_t DD = (size_t)D_DIM * D_DIM * 2;
    const size_t DH = (size_t)D_DIM * H_DIM * 2;
    const size_t NROW = (size_t)B_SZ * S_LEN;

    ushort* wkvT[2]; ushort* woT[2]; ushort* w1T[2]; ushort* w2T[2];
    for (int l = 0; l < 2; ++l) {
        wkvT[l] = (ushort*)take(2 * DD);     // [2048][1024]: wk^T | wv^T
        woT[l]  = (ushort*)take(DD);
        w1T[l]  = (ushort*)take(DH);         // [4096][1024]
        w2T[l]  = (ushort*)take(DH);         // [1024][4096]
    }

    float*  h0     = (float*)take(NROW * D_DIM * 4);
    float*  h1     = (float*)take(NROW * D_DIM * 4);
    ushort* hbf    = (ushort*)take(NROW * D_DIM * 2);
    ushort* hresbf = (ushort*)take(NROW * D_DIM * 2);
    ushort* xkv    = (ushort*)take(NROW * 2 * D_DIM * 2);     // [8192][2048]
    ushort* xvt    = (ushort*)take((size_t)D_DIM * NROW * 2); // [1024][8192]
    ushort* hattn  = (ushort*)take(NROW * D_DIM * 2);
    char*   G      = take((size_t)B_SZ * S_LEN * S_LEN * 4 + (size_t)B_SZ * S_LEN * S_LEN * 2);
    float*  scores = (float*)G;
    ushort* probs  = (ushort*)(G + (size_t)B_SZ * S_LEN * S_LEN * 4);
    ushort* tbf    = (ushort*)G;   // FFN hidden aliases scores (disjoint phases)

    for (int l = 0; l < 2; ++l) {
        const float* wk = (const float*)d_in[3 + 5 * l + 0];
        const float* wv = (const float*)d_in[3 + 5 * l + 1];
        const float* wo = (const float*)d_in[3 + 5 * l + 2];
        const float* w1 = (const float*)d_in[3 + 5 * l + 3];
        const float* w2 = (const float*)d_in[3 + 5 * l + 4];
        bt_wtranspose<<<dim3(16, 16), 256, 0, stream>>>(wk, wkvT[l], 1024, 1024);
        bt_wtranspose<<<dim3(16, 16), 256, 0, stream>>>(wv, wkvT[l] + (size_t)D_DIM * D_DIM, 1024, 1024);
        bt_wtranspose<<<dim3(16, 16), 256, 0, stream>>>(wo, woT[l], 1024, 1024);
        bt_wtranspose<<<dim3(64, 16), 256, 0, stream>>>(w1, w1T[l], 1024, 4096);
        bt_wtranspose<<<dim3(16, 64), 256, 0, stream>>>(w2, w2T[l], 4096, 1024);
    }

    bt_embed<<<NROW, 256, 0, stream>>>(tokens, emb, pe, h0, hbf);

    auto layer = [&](int l) {
        // xkv = h @ [wk|wv] : M=8192, N=2048, K=1024; grid 16x64 = 1024 blocks
        bt_gemm<EPI_BF16, false, false, 1><<<dim3(16, 64), 256, 0, stream>>>(
            hbf, wkvT[l], nullptr, xkv, nullptr, D_DIM, D_DIM, 2 * D_DIM, D_DIM, 0, 0, 0);
        // xvt = transpose(xkv[:, 1024:2048]) -> [1024][8192]
        bt_transpose<<<dim3(16, 128), 256, 0, stream>>>(xkv, xvt, (int)NROW, 2 * D_DIM, D_DIM);
        // scores = Q @ xk^T per batch (causal tiles), fp32
        bt_gemm<EPI_F32, true, false, 0><<<dim3(16, 16, B_SZ), 256, 0, stream>>>(
            hbf, xkv, scores, nullptr, nullptr, D_DIM, 2 * D_DIM, S_LEN, D_DIM,
            (size_t)S_LEN * D_DIM, (size_t)S_LEN * 2 * D_DIM, (size_t)S_LEN * S_LEN);
        bt_softmax<<<NROW, 256, 0, stream>>>(scores, probs);
        // h_attn = probs @ xv (B^T = xvt per-batch col slice), causal K-limit
        bt_gemm<EPI_BF16, false, true, 0><<<dim3(8, 16, B_SZ), 256, 0, stream>>>(
            probs, xvt, nullptr, hattn, nullptr, S_LEN, (int)NROW, D_DIM, S_LEN,
            (size_t)S_LEN * S_LEN, (size_t)S_LEN, (size_t)S_LEN * D_DIM);
        // h_res = h + h_attn @ wo : grid 8x64
        bt_gemm<EPI_RES, false, false, 1><<<dim3(8, 64), 256, 0, stream>>>(
            hattn, woT[l], h1, hresbf, h0, D_DIM, D_DIM, D_DIM, D_DIM, 0, 0, 0);
        // t = relu(h_res @ w1) : grid 32x64 = 2048 blocks
        bt_gemm<EPI_RELU, false, false, 1><<<dim3(32, 64), 256, 0, stream>>>(
            hresbf, w1T[l], nullptr, tbf, nullptr, D_DIM, D_DIM, H_DIM, D_DIM, 0, 0, 0);
        // h = h_res + t @ w2 : K=4096; grid 8x64
        bt_gemm<EPI_RES, false, false, 1><<<dim3(8, 64), 256, 0, stream>>>(
            tbf, w2T[l], h0, hbf, h1, H_DIM, H_DIM, D_DIM, H_DIM, 0, 0, 0);
    };
    layer(0);
    layer(1);

    hipMemsetAsync(d_out, 0, (size_t)B_SZ * V_DIM * sizeof(float), stream);
    bt_logits<<<dim3(V_DIM / 256, D_DIM / 128), 256, 0, stream>>>(h0, wout, (float*)d_out);
}

// Round 11
// 876.826 us; speedup vs baseline: 1.0196x; 1.0196x over previous
//
#include <hip/hip_runtime.h>

#define S_LEN 2048
#define D_DIM 1024
#define H_DIM 4096
#define V_DIM 32000
#define B_SZ  4

typedef float  f32x4  __attribute__((ext_vector_type(4)));
typedef __bf16 bf16x8 __attribute__((ext_vector_type(8)));

__device__ __forceinline__ ushort f2bf(float f) {
    union { float f; unsigned u; } v; v.f = f;
    unsigned r = v.u + 0x7fffu + ((v.u >> 16) & 1u);
    return (ushort)(r >> 16);
}

// ---------------------------------------------------------------------------
// Weight transpose + fp32->bf16 convert: in fp32 [R][C] -> out bf16 [C][R]
// ---------------------------------------------------------------------------
__global__ void bt_wtranspose(const float* __restrict__ in, ushort* __restrict__ out,
                              int R, int C) {
    __shared__ ushort s[64][65];
    int r0 = blockIdx.y * 64, c0 = blockIdx.x * 64;
    int t = threadIdx.x;
    int lr = t >> 2, lc4 = (t & 3) * 16;
    const float* src = in + (size_t)(r0 + lr) * C + c0 + lc4;
#pragma unroll
    for (int j = 0; j < 4; ++j) {
        float4 v = ((const float4*)src)[j];
        s[lr][lc4 + 4 * j + 0] = f2bf(v.x);
        s[lr][lc4 + 4 * j + 1] = f2bf(v.y);
        s[lr][lc4 + 4 * j + 2] = f2bf(v.z);
        s[lr][lc4 + 4 * j + 3] = f2bf(v.w);
    }
    __syncthreads();
    int oc = t >> 2, orr = (t & 3) * 16;
    ushort tmp[16] __attribute__((aligned(16)));
#pragma unroll
    for (int j = 0; j < 16; ++j) tmp[j] = s[orr + j][oc];
    ushort* dst = out + (size_t)(c0 + oc) * R + r0 + orr;
    *(uint4*)dst        = *(uint4*)tmp;
    *(uint4*)(dst + 8)  = *(uint4*)(tmp + 8);
}

// ---------------------------------------------------------------------------
// bf16 transpose of a column slice: out[c][r] = in[r][coff + c]
// ---------------------------------------------------------------------------
__global__ void bt_transpose(const ushort* __restrict__ in, ushort* __restrict__ out,
                             int R, int ldin, int coff) {
    __shared__ ushort s[64][65];
    int r0 = blockIdx.y * 64, c0 = blockIdx.x * 64;
    int t = threadIdx.x;
    int lr = t >> 2, lc = (t & 3) * 16;
    const ushort* src = in + (size_t)(r0 + lr) * ldin + coff + c0 + lc;
    uint4 v0 = ((const uint4*)src)[0];
    uint4 v1 = ((const uint4*)src)[1];
    ushort tin[16] __attribute__((aligned(16)));
    *(uint4*)tin = v0; *(uint4*)(tin + 8) = v1;
#pragma unroll
    for (int j = 0; j < 16; ++j) s[lr][lc + j] = tin[j];
    __syncthreads();
    int oc = t >> 2, orr = (t & 3) * 16;
    ushort tmp[16] __attribute__((aligned(16)));
#pragma unroll
    for (int j = 0; j < 16; ++j) tmp[j] = s[orr + j][oc];
    ushort* dst = out + (size_t)(c0 + oc) * R + r0 + orr;
    *(uint4*)dst       = *(uint4*)tmp;
    *(uint4*)(dst + 8) = *(uint4*)(tmp + 8);
}

// ---------------------------------------------------------------------------
// Embedding + positional encoding
// ---------------------------------------------------------------------------
__global__ void bt_embed(const int* __restrict__ tokens, const float* __restrict__ emb,
                         const float* __restrict__ pe, float* __restrict__ h,
                         ushort* __restrict__ hbf) {
    int row = blockIdx.x;
    int s   = row & (S_LEN - 1);
    int tok = tokens[row];
    int t   = threadIdx.x;
    float4 v = ((const float4*)(emb + (size_t)tok * D_DIM))[t];
    float4 p = ((const float4*)(pe + (size_t)s * D_DIM))[t];
    v.x += p.x; v.y += p.y; v.z += p.z; v.w += p.w;
    ((float4*)(h + (size_t)row * D_DIM))[t] = v;
    uint2 pk;
    pk.x = (unsigned)f2bf(v.x) | ((unsigned)f2bf(v.y) << 16);
    pk.y = (unsigned)f2bf(v.z) | ((unsigned)f2bf(v.w) << 16);
    ((uint2*)(hbf + (size_t)row * D_DIM))[t] = pk;
}

// ---------------------------------------------------------------------------
// m97-structure GEMM, 4+ blocks/CU: 128x128 tile, 4 waves (2x2), acc 4x4,
// SINGLE 32KB LDS buffer, two __syncthreads per K=64 step, compiler-managed
// waitcnts. __launch_bounds__(256,4): 4-5 co-resident blocks/CU so the
// per-K-step vmcnt(0) drain (~600-900cy HBM latency) is covered by other
// blocks' MFMA work (m114 inter-block overlap -- the knob all prior rounds
// left at 2). XCD band swizzle kept (R4: -70% FETCH).
// ---------------------------------------------------------------------------
#define EPI_F32  0
#define EPI_BF16 1
#define EPI_RELU 2
#define EPI_RES  3

#define AS1 __attribute__((address_space(1)))
#define AS3 __attribute__((address_space(3)))

template <int EPI, bool CSKIP, bool KLIM, int SWZ>
__global__ __launch_bounds__(256, 4)
void bt_gemm(const ushort* __restrict__ A, const ushort* __restrict__ B,
             float* Cf, ushort* Cb, const float* __restrict__ Res,
             int lda, int ldb, int ldc, int K,
             size_t strideA, size_t strideB, size_t strideC) {
    __shared__ ushort sA[128 * 64];
    __shared__ ushort sB[128 * 64];

    int bm, bn;
    if (SWZ == 1) {               // XCD owns a band of bm rows (gy % 8 == 0)
        int gx = gridDim.x, gy = gridDim.y;
        int id = blockIdx.y * gx + blockIdx.x;
        int xcd = id & 7, slot = id >> 3;
        int bandH = gy >> 3;
        bm = xcd * bandH + (slot % bandH);
        bn = slot / bandH;
    } else { bm = blockIdx.y; bn = blockIdx.x; }

    if (CSKIP && bn > bm) return;       // causal: tile fully above diagonal

    const int tid  = threadIdx.x;
    const int lane = tid & 63;
    const int wv   = tid >> 6;
    const int wr   = wv >> 1, wc = wv & 1;
    const int r15  = lane & 15, r4 = lane >> 4;

    const ushort* Ab = A + strideA * blockIdx.z + (size_t)bm * 128 * lda;
    const ushort* Bb = B + strideB * blockIdx.z + (size_t)bn * 128 * ldb;

    int ktiles = K >> 6;
    if (KLIM) { int lim = (bm + 1) * 2; if (lim < ktiles) ktiles = lim; }

    f32x4 acc[4][4];
#pragma unroll
    for (int m = 0; m < 4; ++m)
#pragma unroll
        for (int n = 0; n < 4; ++n) acc[m][n] = (f32x4){0.f, 0.f, 0.f, 0.f};

    const int srow = wv * 8 + (lane >> 3);  // staging row within 32-row round
    const int sout = lane & 7;              // destination 16B slot within row

    for (int kt = 0; kt < ktiles; ++kt) {
        __syncthreads();                    // protect LDS from overwrite
        const ushort* Ak = Ab + kt * 64;
        const ushort* Bk = Bb + kt * 64;
#pragma unroll
        for (int j = 0; j < 4; ++j) {
            int row = j * 32 + srow;
            int si  = sout ^ (row & 7);     // pre-swizzled global source slot
            __builtin_amdgcn_global_load_lds(
                (const AS1 void*)(Ak + (size_t)row * lda + si * 8),
                (AS3 void*)(sA + j * 2048 + wv * 512), 16, 0, 0);
        }
#pragma unroll
        for (int j = 0; j < 4; ++j) {
            int row = j * 32 + srow;
            int si  = sout ^ (row & 7);
            __builtin_amdgcn_global_load_lds(
                (const AS1 void*)(Bk + (size_t)row * ldb + si * 8),
                (AS3 void*)(sB + j * 2048 + wv * 512), 16, 0, 0);
        }
        __syncthreads();                    // drains vmcnt + barrier
#pragma unroll
        for (int kk = 0; kk < 2; ++kk) {
            bf16x8 af[4], bv[4];
            int s = kk * 4 + r4;
#pragma unroll
            for (int m = 0; m < 4; ++m) {
                int row = wr * 64 + m * 16 + r15;
                af[m] = *(const bf16x8*)(sA + (size_t)row * 64 + (size_t)((s ^ (row & 7)) * 8));
            }
#pragma unroll
            for (int n = 0; n < 4; ++n) {
                int col = wc * 64 + n * 16 + r15;
                bv[n] = *(const bf16x8*)(sB + (size_t)col * 64 + (size_t)((s ^ (col & 7)) * 8));
            }
#pragma unroll
            for (int m = 0; m < 4; ++m)
#pragma unroll
                for (int n = 0; n < 4; ++n)
                    acc[m][n] = __builtin_amdgcn_mfma_f32_16x16x32_bf16(af[m], bv[n], acc[m][n], 0, 0, 0);
        }
    }

    // epilogue: frag row = 4*(lane>>4)+r, col = lane&15
    size_t cz = strideC * blockIdx.z;
    const int rowb = bm * 128 + wr * 64 + r4 * 4;
    const int colb = bn * 128 + wc * 64 + r15;
#pragma unroll
    for (int m = 0; m < 4; ++m) {
#pragma unroll
        for (int r = 0; r < 4; ++r) {
            int row = rowb + m * 16 + r;
            size_t base = cz + (size_t)row * ldc + colb;
#pragma unroll
            for (int n = 0; n < 4; ++n) {
                float v = acc[m][n][r];
                size_t idx = base + n * 16;
                if (EPI == EPI_F32)       Cf[idx] = v;
                else if (EPI == EPI_BF16) Cb[idx] = f2bf(v);
                else if (EPI == EPI_RELU) Cb[idx] = f2bf(fmaxf(v, 0.f));
                else { float o = v + Res[idx]; Cf[idx] = o; Cb[idx] = f2bf(o); }
            }
        }
    }
}

// ---------------------------------------------------------------------------
// Causal row softmax: scores fp32 [B][S][S] -> probs bf16 (zeros above diag)
// ---------------------------------------------------------------------------
__device__ __forceinline__ float wred_max(float v) {
#pragma unroll
    for (int off = 32; off; off >>= 1) v = fmaxf(v, __shfl_xor(v, off));
    return v;
}
__device__ __forceinline__ float wred_sum(float v) {
#pragma unroll
    for (int off = 32; off; off >>= 1) v += __shfl_xor(v, off);
    return v;
}

__global__ void bt_softmax(const float* __restrict__ scores, ushort* __restrict__ probs) {
    int row = blockIdx.x;
    int s   = row & (S_LEN - 1);
    const float* src = scores + (size_t)row * S_LEN;
    ushort*      dst = probs  + (size_t)row * S_LEN;
    int tid = threadIdx.x;
    int nvalid = s + 1;

    float vals[8];
    float mx = -1e30f;
#pragma unroll
    for (int j = 0; j < 8; ++j) {
        int t = tid + j * 256;
        float v = (t < nvalid) ? src[t] * 0.03125f : -1e30f;
        vals[j] = v;
        mx = fmaxf(mx, v);
    }
    __shared__ float red[4], red2[4];
    mx = wred_max(mx);
    if ((tid & 63) == 0) red[tid >> 6] = mx;
    __syncthreads();
    mx = fmaxf(fmaxf(red[0], red[1]), fmaxf(red[2], red[3]));

    float sum = 0.f, ps[8];
#pragma unroll
    for (int j = 0; j < 8; ++j) {
        float p = exp2f((vals[j] - mx) * 1.44269504f);
        ps[j] = p; sum += p;
    }
    sum = wred_sum(sum);
    if ((tid & 63) == 0) red2[tid >> 6] = sum;
    __syncthreads();
    sum = red2[0] + red2[1] + red2[2] + red2[3];
    float inv = 1.0f / sum;
#pragma unroll
    for (int j = 0; j < 8; ++j) {
        int t = tid + j * 256;
        dst[t] = (t < nvalid) ? f2bf(ps[j] * inv) : (ushort)0;
    }
}

// ---------------------------------------------------------------------------
// Last-token logits
// ---------------------------------------------------------------------------
__global__ void bt_logits(const float* __restrict__ h, const float* __restrict__ wout,
                          float* __restrict__ out) {
    __shared__ float hl[4][128];
    int tid = threadIdx.x;
    int d0 = blockIdx.y * 128;
    if (tid < 128) {
#pragma unroll
        for (int b = 0; b < 4; ++b)
            hl[b][tid] = h[((size_t)b * S_LEN + (S_LEN - 1)) * D_DIM + d0 + tid];
    }
    __syncthreads();
    int v = blockIdx.x * 256 + tid;
    float a0 = 0, a1 = 0, a2 = 0, a3 = 0;
    for (int j = 0; j < 128; ++j) {
        float w = wout[(size_t)(d0 + j) * V_DIM + v];
        a0 += hl[0][j] * w; a1 += hl[1][j] * w;
        a2 += hl[2][j] * w; a3 += hl[3][j] * w;
    }
    atomicAdd(out + v, a0);
    atomicAdd(out + V_DIM + v, a1);
    atomicAdd(out + 2 * V_DIM + v, a2);
    atomicAdd(out + 3 * V_DIM + v, a3);
}

// ---------------------------------------------------------------------------
extern "C" void kernel_launch(void* const* d_in, const int* in_sizes, int n_in,
                              void* d_out, int out_size, void* d_ws, size_t ws_size,
                              hipStream_t stream) {
    const int*   tokens = (const int*)d_in[0];
    const float* emb    = (const float*)d_in[1];
    const float* pe     = (const float*)d_in[2];
    const float* wout = (const float*)d_in[13];

    char* w = (char*)d_ws;
    size_t o = 0;
    auto take = [&](size_t sz) { char* p = w + o; o += (sz + 255) & ~(size_t)255; return p; };

    const size_t DD = (size_t)D_DIM * D_DIM * 2;
    const size_t DH = (size_t)D_DIM * H_DIM * 2;
    const size_t NROW = (size_t)B_SZ * S_LEN;

    ushort* wkvT[2]; ushort* woT[2]; ushort* w1T[2]; ushort* w2T[2];
    for (int l = 0; l < 2; ++l) {
        wkvT[l] = (ushort*)take(2 * DD);     // [2048][1024]: wk^T | wv^T
        woT[l]  = (ushort*)take(DD);
        w1T[l]  = (ushort*)take(DH);         // [4096][1024]
        w2T[l]  = (ushort*)take(DH);         // [1024][4096]
    }

    float*  h0     = (float*)take(NROW * D_DIM * 4);
    float*  h1     = (float*)take(NROW * D_DIM * 4);
    ushort* hbf    = (ushort*)take(NROW * D_DIM * 2);
    ushort* hresbf = (ushort*)take(NROW * D_DIM * 2);
    ushort* xkv    = (ushort*)take(NROW * 2 * D_DIM * 2);     // [8192][2048]
    ushort* xvt    = (ushort*)take((size_t)D_DIM * NROW * 2); // [1024][8192]
    ushort* hattn  = (ushort*)take(NROW * D_DIM * 2);
    char*   G      = take((size_t)B_SZ * S_LEN * S_LEN * 4 + (size_t)B_SZ * S_LEN * S_LEN * 2);
    float*  scores = (float*)G;
    ushort* probs  = (ushort*)(G + (size_t)B_SZ * S_LEN * S_LEN * 4);
    ushort* tbf    = (ushort*)G;   // FFN hidden aliases scores (disjoint phases)

    for (int l = 0; l < 2; ++l) {
        const float* wk = (const float*)d_in[3 + 5 * l + 0];
        const float* wv = (const float*)d_in[3 + 5 * l + 1];
        const float* wo = (const float*)d_in[3 + 5 * l + 2];
        const float* w1 = (const float*)d_in[3 + 5 * l + 3];
        const float* w2 = (const float*)d_in[3 + 5 * l + 4];
        bt_wtranspose<<<dim3(16, 16), 256, 0, stream>>>(wk, wkvT[l], 1024, 1024);
        bt_wtranspose<<<dim3(16, 16), 256, 0, stream>>>(wv, wkvT[l] + (size_t)D_DIM * D_DIM, 1024, 1024);
        bt_wtranspose<<<dim3(16, 16), 256, 0, stream>>>(wo, woT[l], 1024, 1024);
        bt_wtranspose<<<dim3(64, 16), 256, 0, stream>>>(w1, w1T[l], 1024, 4096);
        bt_wtranspose<<<dim3(16, 64), 256, 0, stream>>>(w2, w2T[l], 4096, 1024);
    }

    bt_embed<<<NROW, 256, 0, stream>>>(tokens, emb, pe, h0, hbf);

    auto layer = [&](int l) {
        // xkv = h @ [wk|wv] : M=8192, N=2048, K=1024; grid 16x64 = 1024 blocks
        bt_gemm<EPI_BF16, false, false, 1><<<dim3(16, 64), 256, 0, stream>>>(
            hbf, wkvT[l], nullptr, xkv, nullptr, D_DIM, D_DIM, 2 * D_DIM, D_DIM, 0, 0, 0);
        // xvt = transpose(xkv[:, 1024:2048]) -> [1024][8192]
        bt_transpose<<<dim3(16, 128), 256, 0, stream>>>(xkv, xvt, (int)NROW, 2 * D_DIM, D_DIM);
        // scores = Q @ xk^T per batch (causal tiles), fp32
        bt_gemm<EPI_F32, true, false, 0><<<dim3(16, 16, B_SZ), 256, 0, stream>>>(
            hbf, xkv, scores, nullptr, nullptr, D_DIM, 2 * D_DIM, S_LEN, D_DIM,
            (size_t)S_LEN * D_DIM, (size_t)S_LEN * 2 * D_DIM, (size_t)S_LEN * S_LEN);
        bt_softmax<<<NROW, 256, 0, stream>>>(scores, probs);
        // h_attn = probs @ xv (B^T = xvt per-batch col slice), causal K-limit
        bt_gemm<EPI_BF16, false, true, 0><<<dim3(8, 16, B_SZ), 256, 0, stream>>>(
            probs, xvt, nullptr, hattn, nullptr, S_LEN, (int)NROW, D_DIM, S_LEN,
            (size_t)S_LEN * S_LEN, (size_t)S_LEN, (size_t)S_LEN * D_DIM);
        // h_res = h + h_attn @ wo : grid 8x64
        bt_gemm<EPI_RES, false, false, 1><<<dim3(8, 64), 256, 0, stream>>>(
            hattn, woT[l], h1, hresbf, h0, D_DIM, D_DIM, D_DIM, D_DIM, 0, 0, 0);
        // t = relu(h_res @ w1) : grid 32x64 = 2048 blocks
        bt_gemm<EPI_RELU, false, false, 1><<<dim3(32, 64), 256, 0, stream>>>(
            hresbf, w1T[l], nullptr, tbf, nullptr, D_DIM, D_DIM, H_DIM, D_DIM, 0, 0, 0);
        // h = h_res + t @ w2 : K=4096; grid 8x64
        bt_gemm<EPI_RES, false, false, 1><<<dim3(8, 64), 256, 0, stream>>>(
            tbf, w2T[l], h0, hbf, h1, H_DIM, H_DIM, D_DIM, H_DIM, 0, 0, 0);
    };
    layer(0);
    layer(1);

    hipMemsetAsync(d_out, 0, (size_t)B_SZ * V_DIM * sizeof(float), stream);
    bt_logits<<<dim3(V_DIM / 256, D_DIM / 128), 256, 0, stream>>>(h0, wout, (float*)d_out);
}

// Round 12
// 844.003 us; speedup vs baseline: 1.0592x; 1.0389x over previous
//
#include <hip/hip_runtime.h>

#define S_LEN 2048
#define D_DIM 1024
#define H_DIM 4096
#define V_DIM 32000
#define B_SZ  4

typedef float  f32x4  __attribute__((ext_vector_type(4)));
typedef __bf16 bf16x8 __attribute__((ext_vector_type(8)));

__device__ __forceinline__ ushort f2bf(float f) {
    union { float f; unsigned u; } v; v.f = f;
    unsigned r = v.u + 0x7fffu + ((v.u >> 16) & 1u);
    return (ushort)(r >> 16);
}

// ---------------------------------------------------------------------------
// Weight transpose + fp32->bf16 convert: in fp32 [R][C] -> out bf16 [C][R]
// ---------------------------------------------------------------------------
__global__ void bt_wtranspose(const float* __restrict__ in, ushort* __restrict__ out,
                              int R, int C) {
    __shared__ ushort s[64][65];
    int r0 = blockIdx.y * 64, c0 = blockIdx.x * 64;
    int t = threadIdx.x;
    int lr = t >> 2, lc4 = (t & 3) * 16;
    const float* src = in + (size_t)(r0 + lr) * C + c0 + lc4;
#pragma unroll
    for (int j = 0; j < 4; ++j) {
        float4 v = ((const float4*)src)[j];
        s[lr][lc4 + 4 * j + 0] = f2bf(v.x);
        s[lr][lc4 + 4 * j + 1] = f2bf(v.y);
        s[lr][lc4 + 4 * j + 2] = f2bf(v.z);
        s[lr][lc4 + 4 * j + 3] = f2bf(v.w);
    }
    __syncthreads();
    int oc = t >> 2, orr = (t & 3) * 16;
    ushort tmp[16] __attribute__((aligned(16)));
#pragma unroll
    for (int j = 0; j < 16; ++j) tmp[j] = s[orr + j][oc];
    ushort* dst = out + (size_t)(c0 + oc) * R + r0 + orr;
    *(uint4*)dst        = *(uint4*)tmp;
    *(uint4*)(dst + 8)  = *(uint4*)(tmp + 8);
}

// ---------------------------------------------------------------------------
// bf16 transpose of a column slice: out[c][r] = in[r][coff + c]
// ---------------------------------------------------------------------------
__global__ void bt_transpose(const ushort* __restrict__ in, ushort* __restrict__ out,
                             int R, int ldin, int coff) {
    __shared__ ushort s[64][65];
    int r0 = blockIdx.y * 64, c0 = blockIdx.x * 64;
    int t = threadIdx.x;
    int lr = t >> 2, lc = (t & 3) * 16;
    const ushort* src = in + (size_t)(r0 + lr) * ldin + coff + c0 + lc;
    uint4 v0 = ((const uint4*)src)[0];
    uint4 v1 = ((const uint4*)src)[1];
    ushort tin[16] __attribute__((aligned(16)));
    *(uint4*)tin = v0; *(uint4*)(tin + 8) = v1;
#pragma unroll
    for (int j = 0; j < 16; ++j) s[lr][lc + j] = tin[j];
    __syncthreads();
    int oc = t >> 2, orr = (t & 3) * 16;
    ushort tmp[16] __attribute__((aligned(16)));
#pragma unroll
    for (int j = 0; j < 16; ++j) tmp[j] = s[orr + j][oc];
    ushort* dst = out + (size_t)(c0 + oc) * R + r0 + orr;
    *(uint4*)dst       = *(uint4*)tmp;
    *(uint4*)(dst + 8) = *(uint4*)(tmp + 8);
}

// ---------------------------------------------------------------------------
// Embedding + positional encoding
// ---------------------------------------------------------------------------
__global__ void bt_embed(const int* __restrict__ tokens, const float* __restrict__ emb,
                         const float* __restrict__ pe, float* __restrict__ h,
                         ushort* __restrict__ hbf) {
    int row = blockIdx.x;
    int s   = row & (S_LEN - 1);
    int tok = tokens[row];
    int t   = threadIdx.x;
    float4 v = ((const float4*)(emb + (size_t)tok * D_DIM))[t];
    float4 p = ((const float4*)(pe + (size_t)s * D_DIM))[t];
    v.x += p.x; v.y += p.y; v.z += p.z; v.w += p.w;
    ((float4*)(h + (size_t)row * D_DIM))[t] = v;
    uint2 pk;
    pk.x = (unsigned)f2bf(v.x) | ((unsigned)f2bf(v.y) << 16);
    pk.y = (unsigned)f2bf(v.z) | ((unsigned)f2bf(v.w) << 16);
    ((uint2*)(hbf + (size_t)row * D_DIM))[t] = pk;
}

// ---------------------------------------------------------------------------
// m97-structure GEMM, BM x BN templated. 4 waves (2x2), acc (BM/32)x(BN/32),
// single LDS buffer, two __syncthreads per K=64 step, compiler-managed
// waitcnts. BMxBN=128x64 -> 24KB LDS, grid doubles: the N=1024 GEMMs (FFN2,
// wo, PV) were grid-capped at 512 blocks = 2 blocks/CU (the actual occupancy
// limiter R11 exposed); 128x64 gives 1024 blocks = 4-6 blocks/CU so
// co-resident blocks cover each other's staging drains (m114).
// XCD band swizzle kept (R4: -70% FETCH).
// ---------------------------------------------------------------------------
#define EPI_F32  0
#define EPI_BF16 1
#define EPI_RELU 2
#define EPI_RES  3

#define AS1 __attribute__((address_space(1)))
#define AS3 __attribute__((address_space(3)))

template <int BM, int BN, int EPI, bool CSKIP, bool KLIM, int SWZ>
__global__ __launch_bounds__(256, 4)
void bt_gemm(const ushort* __restrict__ A, const ushort* __restrict__ B,
             float* Cf, ushort* Cb, const float* __restrict__ Res,
             int lda, int ldb, int ldc, int K,
             size_t strideA, size_t strideB, size_t strideC) {
    constexpr int MR = BM / 32;      // frags per wave in m (wave tile BM/2)
    constexpr int NR = BN / 32;      // frags per wave in n (wave tile BN/2)

    __shared__ ushort sA[BM * 64];
    __shared__ ushort sB[BN * 64];

    int bm, bn;
    if (SWZ == 1) {               // XCD owns a band of bm rows (gy % 8 == 0)
        int gx = gridDim.x, gy = gridDim.y;
        int id = blockIdx.y * gx + blockIdx.x;
        int xcd = id & 7, slot = id >> 3;
        int bandH = gy >> 3;
        bm = xcd * bandH + (slot % bandH);
        bn = slot / bandH;
    } else { bm = blockIdx.y; bn = blockIdx.x; }

    if (CSKIP && bn * BN >= (bm + 1) * BM) return;   // tile above diagonal

    const int tid  = threadIdx.x;
    const int lane = tid & 63;
    const int wv   = tid >> 6;
    const int wr   = wv >> 1, wc = wv & 1;
    const int r15  = lane & 15, r4 = lane >> 4;

    const ushort* Ab = A + strideA * blockIdx.z + (size_t)bm * BM * lda;
    const ushort* Bb = B + strideB * blockIdx.z + (size_t)bn * BN * ldb;

    int ktiles = K >> 6;
    if (KLIM) { int lim = (bm + 1) * (BM / 64); if (lim < ktiles) ktiles = lim; }

    f32x4 acc[MR][NR];
#pragma unroll
    for (int m = 0; m < MR; ++m)
#pragma unroll
        for (int n = 0; n < NR; ++n) acc[m][n] = (f32x4){0.f, 0.f, 0.f, 0.f};

    const int srow = wv * 8 + (lane >> 3);  // staging row within 32-row round
    const int sout = lane & 7;              // destination 16B slot within row

    for (int kt = 0; kt < ktiles; ++kt) {
        __syncthreads();                    // protect LDS from overwrite
        const ushort* Ak = Ab + kt * 64;
        const ushort* Bk = Bb + kt * 64;
#pragma unroll
        for (int j = 0; j < BM / 32; ++j) {
            int row = j * 32 + srow;
            int si  = sout ^ (row & 7);     // pre-swizzled global source slot
            __builtin_amdgcn_global_load_lds(
                (const AS1 void*)(Ak + (size_t)row * lda + si * 8),
                (AS3 void*)(sA + j * 2048 + wv * 512), 16, 0, 0);
        }
#pragma unroll
        for (int j = 0; j < BN / 32; ++j) {
            int row = j * 32 + srow;
            int si  = sout ^ (row & 7);
            __builtin_amdgcn_global_load_lds(
                (const AS1 void*)(Bk + (size_t)row * ldb + si * 8),
                (AS3 void*)(sB + j * 2048 + wv * 512), 16, 0, 0);
        }
        __syncthreads();                    // drains vmcnt + barrier
#pragma unroll
        for (int kk = 0; kk < 2; ++kk) {
            bf16x8 af[MR], bv[NR];
            int s = kk * 4 + r4;
#pragma unroll
            for (int m = 0; m < MR; ++m) {
                int row = wr * (BM / 2) + m * 16 + r15;
                af[m] = *(const bf16x8*)(sA + (size_t)row * 64 + (size_t)((s ^ (row & 7)) * 8));
            }
#pragma unroll
            for (int n = 0; n < NR; ++n) {
                int col = wc * (BN / 2) + n * 16 + r15;
                bv[n] = *(const bf16x8*)(sB + (size_t)col * 64 + (size_t)((s ^ (col & 7)) * 8));
            }
#pragma unroll
            for (int m = 0; m < MR; ++m)
#pragma unroll
                for (int n = 0; n < NR; ++n)
                    acc[m][n] = __builtin_amdgcn_mfma_f32_16x16x32_bf16(af[m], bv[n], acc[m][n], 0, 0, 0);
        }
    }

    // epilogue: frag row = 4*(lane>>4)+r, col = lane&15
    size_t cz = strideC * blockIdx.z;
    const int rowb = bm * BM + wr * (BM / 2) + r4 * 4;
    const int colb = bn * BN + wc * (BN / 2) + r15;
#pragma unroll
    for (int m = 0; m < MR; ++m) {
#pragma unroll
        for (int r = 0; r < 4; ++r) {
            int row = rowb + m * 16 + r;
            size_t base = cz + (size_t)row * ldc + colb;
#pragma unroll
            for (int n = 0; n < NR; ++n) {
                float v = acc[m][n][r];
                size_t idx = base + n * 16;
                if (EPI == EPI_F32)       Cf[idx] = v;
                else if (EPI == EPI_BF16) Cb[idx] = f2bf(v);
                else if (EPI == EPI_RELU) Cb[idx] = f2bf(fmaxf(v, 0.f));
                else { float o = v + Res[idx]; Cf[idx] = o; Cb[idx] = f2bf(o); }
            }
        }
    }
}

// ---------------------------------------------------------------------------
// Causal row softmax: scores fp32 [B][S][S] -> probs bf16 (zeros above diag)
// ---------------------------------------------------------------------------
__device__ __forceinline__ float wred_max(float v) {
#pragma unroll
    for (int off = 32; off; off >>= 1) v = fmaxf(v, __shfl_xor(v, off));
    return v;
}
__device__ __forceinline__ float wred_sum(float v) {
#pragma unroll
    for (int off = 32; off; off >>= 1) v += __shfl_xor(v, off);
    return v;
}

__global__ void bt_softmax(const float* __restrict__ scores, ushort* __restrict__ probs) {
    int row = blockIdx.x;
    int s   = row & (S_LEN - 1);
    const float* src = scores + (size_t)row * S_LEN;
    ushort*      dst = probs  + (size_t)row * S_LEN;
    int tid = threadIdx.x;
    int nvalid = s + 1;

    float vals[8];
    float mx = -1e30f;
#pragma unroll
    for (int j = 0; j < 8; ++j) {
        int t = tid + j * 256;
        float v = (t < nvalid) ? src[t] * 0.03125f : -1e30f;
        vals[j] = v;
        mx = fmaxf(mx, v);
    }
    __shared__ float red[4], red2[4];
    mx = wred_max(mx);
    if ((tid & 63) == 0) red[tid >> 6] = mx;
    __syncthreads();
    mx = fmaxf(fmaxf(red[0], red[1]), fmaxf(red[2], red[3]));

    float sum = 0.f, ps[8];
#pragma unroll
    for (int j = 0; j < 8; ++j) {
        float p = exp2f((vals[j] - mx) * 1.44269504f);
        ps[j] = p; sum += p;
    }
    sum = wred_sum(sum);
    if ((tid & 63) == 0) red2[tid >> 6] = sum;
    __syncthreads();
    sum = red2[0] + red2[1] + red2[2] + red2[3];
    float inv = 1.0f / sum;
#pragma unroll
    for (int j = 0; j < 8; ++j) {
        int t = tid + j * 256;
        dst[t] = (t < nvalid) ? f2bf(ps[j] * inv) : (ushort)0;
    }
}

// ---------------------------------------------------------------------------
// Last-token logits
// ---------------------------------------------------------------------------
__global__ void bt_logits(const float* __restrict__ h, const float* __restrict__ wout,
                          float* __restrict__ out) {
    __shared__ float hl[4][128];
    int tid = threadIdx.x;
    int d0 = blockIdx.y * 128;
    if (tid < 128) {
#pragma unroll
        for (int b = 0; b < 4; ++b)
            hl[b][tid] = h[((size_t)b * S_LEN + (S_LEN - 1)) * D_DIM + d0 + tid];
    }
    __syncthreads();
    int v = blockIdx.x * 256 + tid;
    float a0 = 0, a1 = 0, a2 = 0, a3 = 0;
    for (int j = 0; j < 128; ++j) {
        float w = wout[(size_t)(d0 + j) * V_DIM + v];
        a0 += hl[0][j] * w; a1 += hl[1][j] * w;
        a2 += hl[2][j] * w; a3 += hl[3][j] * w;
    }
    atomicAdd(out + v, a0);
    atomicAdd(out + V_DIM + v, a1);
    atomicAdd(out + 2 * V_DIM + v, a2);
    atomicAdd(out + 3 * V_DIM + v, a3);
}

// ---------------------------------------------------------------------------
extern "C" void kernel_launch(void* const* d_in, const int* in_sizes, int n_in,
                              void* d_out, int out_size, void* d_ws, size_t ws_size,
                              hipStream_t stream) {
    const int*   tokens = (const int*)d_in[0];
    const float* emb    = (const float*)d_in[1];
    const float* pe     = (const float*)d_in[2];
    const float* wout = (const float*)d_in[13];

    char* w = (char*)d_ws;
    size_t o = 0;
    auto take = [&](size_t sz) { char* p = w + o; o += (sz + 255) & ~(size_t)255; return p; };

    const size_t DD = (size_t)D_DIM * D_DIM * 2;
    const size_t DH = (size_t)D_DIM * H_DIM * 2;
    const size_t NROW = (size_t)B_SZ * S_LEN;

    ushort* wkvT[2]; ushort* woT[2]; ushort* w1T[2]; ushort* w2T[2];
    for (int l = 0; l < 2; ++l) {
        wkvT[l] = (ushort*)take(2 * DD);     // [2048][1024]: wk^T | wv^T
        woT[l]  = (ushort*)take(DD);
        w1T[l]  = (ushort*)take(DH);         // [4096][1024]
        w2T[l]  = (ushort*)take(DH);         // [1024][4096]
    }

    float*  h0     = (float*)take(NROW * D_DIM * 4);
    float*  h1     = (float*)take(NROW * D_DIM * 4);
    ushort* hbf    = (ushort*)take(NROW * D_DIM * 2);
    ushort* hresbf = (ushort*)take(NROW * D_DIM * 2);
    ushort* xkv    = (ushort*)take(NROW * 2 * D_DIM * 2);     // [8192][2048]
    ushort* xvt    = (ushort*)take((size_t)D_DIM * NROW * 2); // [1024][8192]
    ushort* hattn  = (ushort*)take(NROW * D_DIM * 2);
    char*   G      = take((size_t)B_SZ * S_LEN * S_LEN * 4 + (size_t)B_SZ * S_LEN * S_LEN * 2);
    float*  scores = (float*)G;
    ushort* probs  = (ushort*)(G + (size_t)B_SZ * S_LEN * S_LEN * 4);
    ushort* tbf    = (ushort*)G;   // FFN hidden aliases scores (disjoint phases)

    for (int l = 0; l < 2; ++l) {
        const float* wk = (const float*)d_in[3 + 5 * l + 0];
        const float* wv = (const float*)d_in[3 + 5 * l + 1];
        const float* wo = (const float*)d_in[3 + 5 * l + 2];
        const float* w1 = (const float*)d_in[3 + 5 * l + 3];
        const float* w2 = (const float*)d_in[3 + 5 * l + 4];
        bt_wtranspose<<<dim3(16, 16), 256, 0, stream>>>(wk, wkvT[l], 1024, 1024);
        bt_wtranspose<<<dim3(16, 16), 256, 0, stream>>>(wv, wkvT[l] + (size_t)D_DIM * D_DIM, 1024, 1024);
        bt_wtranspose<<<dim3(16, 16), 256, 0, stream>>>(wo, woT[l], 1024, 1024);
        bt_wtranspose<<<dim3(64, 16), 256, 0, stream>>>(w1, w1T[l], 1024, 4096);
        bt_wtranspose<<<dim3(16, 64), 256, 0, stream>>>(w2, w2T[l], 4096, 1024);
    }

    bt_embed<<<NROW, 256, 0, stream>>>(tokens, emb, pe, h0, hbf);

    auto layer = [&](int l) {
        // xkv = h @ [wk|wv] : M=8192, N=2048; grid 16x64 = 1024 blocks
        bt_gemm<128, 128, EPI_BF16, false, false, 1><<<dim3(16, 64), 256, 0, stream>>>(
            hbf, wkvT[l], nullptr, xkv, nullptr, D_DIM, D_DIM, 2 * D_DIM, D_DIM, 0, 0, 0);
        // xvt = transpose(xkv[:, 1024:2048]) -> [1024][8192]
        bt_transpose<<<dim3(16, 128), 256, 0, stream>>>(xkv, xvt, (int)NROW, 2 * D_DIM, D_DIM);
        // scores = Q @ xk^T per batch (causal tiles), fp32
        bt_gemm<128, 128, EPI_F32, true, false, 0><<<dim3(16, 16, B_SZ), 256, 0, stream>>>(
            hbf, xkv, scores, nullptr, nullptr, D_DIM, 2 * D_DIM, S_LEN, D_DIM,
            (size_t)S_LEN * D_DIM, (size_t)S_LEN * 2 * D_DIM, (size_t)S_LEN * S_LEN);
        bt_softmax<<<NROW, 256, 0, stream>>>(scores, probs);
        // h_attn = probs @ xv : 128x64 tiles -> grid (16,16,4) = 1024 blocks
        bt_gemm<128, 64, EPI_BF16, false, true, 0><<<dim3(16, 16, B_SZ), 256, 0, stream>>>(
            probs, xvt, nullptr, hattn, nullptr, S_LEN, (int)NROW, D_DIM, S_LEN,
            (size_t)S_LEN * S_LEN, (size_t)S_LEN, (size_t)S_LEN * D_DIM);
        // h_res = h + h_attn @ wo : 128x64 -> grid (16,64) = 1024 blocks
        bt_gemm<128, 64, EPI_RES, false, false, 1><<<dim3(16, 64), 256, 0, stream>>>(
            hattn, woT[l], h1, hresbf, h0, D_DIM, D_DIM, D_DIM, D_DIM, 0, 0, 0);
        // t = relu(h_res @ w1) : grid 32x64 = 2048 blocks
        bt_gemm<128, 128, EPI_RELU, false, false, 1><<<dim3(32, 64), 256, 0, stream>>>(
            hresbf, w1T[l], nullptr, tbf, nullptr, D_DIM, D_DIM, H_DIM, D_DIM, 0, 0, 0);
        // h = h_res + t @ w2 : K=4096; 128x64 -> grid (16,64) = 1024 blocks
        bt_gemm<128, 64, EPI_RES, false, false, 1><<<dim3(16, 64), 256, 0, stream>>>(
            tbf, w2T[l], h0, hbf, h1, H_DIM, H_DIM, D_DIM, H_DIM, 0, 0, 0);
    };
    layer(0);
    layer(1);

    hipMemsetAsync(d_out, 0, (size_t)B_SZ * V_DIM * sizeof(float), stream);
    bt_logits<<<dim3(V_DIM / 256, D_DIM / 128), 256, 0, stream>>>(h0, wout, (float*)d_out);
}